// Round 10
// baseline (1612.420 us; speedup 1.0000x reference)
//
#include <hip/hip_runtime.h>
#include <cstdint>
#include <cstddef>

// Problem constants
#define SENC  128
#define NSTEPS 159          // 128 encoder + 31 decoder
#define HB16  524288        // shorts per h slot (1 MB), tile-major [r][c][128][16]
#define XSLICE 131072       // shorts per r-slice within a slot: 64 tiles x 2048
#define SLAB_ELEMS 55296    // per-c W_hi slab: 36*3*64*8 shorts
#define FRAG_TOTAL 442368   // 64*36*3*64 fragment slots
#define FS 16               // flag stride in dwords (64B lines)

typedef short  short8  __attribute__((ext_vector_type(8)));
typedef float  floatx4 __attribute__((ext_vector_type(4)));
typedef float  f32x4   __attribute__((ext_vector_type(4)));
typedef int    i32x4   __attribute__((ext_vector_type(4)));
typedef unsigned long long u64;

#define MFMA(a, b, c) __builtin_amdgcn_mfma_f32_16x16x32_bf16((a), (b), (c), 0, 0, 0)

// ---------- raw asm memory ops ----------
__device__ __forceinline__ i32x4 ld_nc16(const void* p) {      // bypass L1+L2 (coherence point)
    i32x4 r;
    asm volatile("global_load_dwordx4 %0, %1, off sc0 sc1" : "=&v"(r) : "v"(p) : "memory");
    return r;
}
__device__ __forceinline__ i32x4 ld_sc0_16(const void* p) {    // bypass L1, cache in local L2
    i32x4 r;
    asm volatile("global_load_dwordx4 %0, %1, off sc0" : "=&v"(r) : "v"(p) : "memory");
    return r;
}
// Far-atomic publish (R5): no-return atomic swap executes at the coherence
// point; drain is deferred into next-step region1.
__device__ __forceinline__ void st_swap8(void* p, u64 v) {
    asm volatile("global_atomic_swap_x2 %0, %1, off sc1" :: "v"(p), "v"(v) : "memory");
}
__device__ __forceinline__ void st_swap4(void* p, unsigned v) {
    asm volatile("global_atomic_swap %0, %1, off sc1" :: "v"(p), "v"(v) : "memory");
}
#define WAITVM(N) asm volatile("s_waitcnt vmcnt(" #N ")" ::: "memory")
#define WAITLGKM  asm volatile("s_waitcnt lgkmcnt(0)" ::: "memory")

// ---------- agent-scope relaxed atomics ----------
__device__ __forceinline__ unsigned ldu_dev(const unsigned* p) {
    return __hip_atomic_load(p, __ATOMIC_RELAXED, __HIP_MEMORY_SCOPE_AGENT);
}
__device__ __forceinline__ u64 ldq_dev(const u64* p) {
    return __hip_atomic_load(p, __ATOMIC_RELAXED, __HIP_MEMORY_SCOPE_AGENT);
}
__device__ __forceinline__ void stu_dev(unsigned* p, unsigned v) {
    __hip_atomic_store(p, v, __ATOMIC_RELAXED, __HIP_MEMORY_SCOPE_AGENT);
}

// ---------- workgroup-scope LDS atomics ----------
__device__ __forceinline__ unsigned ld_ws(const unsigned* p) {
    return __hip_atomic_load(p, __ATOMIC_RELAXED, __HIP_MEMORY_SCOPE_WORKGROUP);
}
__device__ __forceinline__ void st_ws(unsigned* p, unsigned v) {
    __hip_atomic_store(p, v, __ATOMIC_RELAXED, __HIP_MEMORY_SCOPE_WORKGROUP);
}
__device__ __forceinline__ unsigned add_ws(unsigned* p, unsigned v) {
    return __hip_atomic_fetch_add(p, v, __ATOMIC_RELAXED, __HIP_MEMORY_SCOPE_WORKGROUP);
}

// ---------- bf16 helpers (RNE) ----------
__device__ __forceinline__ float bf2f(short s) {
    return __uint_as_float(((unsigned)(unsigned short)s) << 16);
}
__device__ __forceinline__ short f2bf(float f) {
    unsigned u = __float_as_uint(f);
    return (short)((u + 0x7FFFu + ((u >> 16) & 1u)) >> 16);
}
__device__ __forceinline__ void f2pair(float f, short& hi, short& lo) {
    hi = f2bf(f);
    lo = f2bf(f - bf2f(hi));
}

__device__ __forceinline__ float sigm(float x) {
    return 1.0f / (1.0f + __expf(-x));
}
__device__ __forceinline__ float tanh_fast(float x) {
    float cx = fminf(fmaxf(x, -15.0f), 15.0f);
    float e = __expf(2.0f * cx);
    return (e - 1.0f) / (e + 1.0f);
}

// ---------- setup: swizzle W_hi (all K) + Wi_lo (x-part only) into fragment order ----------
__global__ void setup_swizzle(const float* __restrict__ Wi, const float* __restrict__ Wh,
                              short* __restrict__ whi, short* __restrict__ wlo_x) {
    const int idx = blockIdx.x * 256 + threadIdx.x;
    if (idx >= FRAG_TOTAL) return;
    const int l    = idx & 63;
    const int rest = idx >> 6;
    const int t    = rest % 3;
    const int ki   = (rest / 3) % 36;
    const int c    = rest / 108;
    const int nrow = t * 1024 + c * 16 + (l & 15);
    const int kb   = ki * 32 + (l >> 4) * 8;
    short8 vh, vl;
#pragma unroll
    for (int j = 0; j < 8; ++j) {
        const int k = kb + j;
        float w = (k < 128) ? Wi[(size_t)nrow * 128 + k]
                            : Wh[(size_t)nrow * 1024 + (k - 128)];
        short h, lo2;
        f2pair(w, h, lo2);
        vh[j] = h; vl[j] = lo2;
    }
    *(short8*)(whi + (size_t)idx * 8) = vh;
    if (ki < 4) {
        const int xi = ((c * 4 + ki) * 3 + t) * 64 + l;
        *(short8*)(wlo_x + (size_t)xi * 8) = vl;
    }
}

// ---------- region-2 pipeline: depth 16, chunk-gated, XCD-rotated ----------
// Chunk kc covers ki = 4+4kc..7+4kc (producers [8kc,8kc+8)). Per-CHAIN gating:
// wave wv4 of chain CH polls same-chain producers [16wv4,16wv4+16) and sets
// s_sub2[CH][wv4]; chunk kc spins on s_sub2[CH][kc>>1]. Same-chain same-XCD
// blocks stay rhythm-correlated (L2 multicast preserved; R8 lesson).
#define HCONS(S, KI) do { \
    short8 ah_ = *(short8*)&hb[S]; \
    const int fo_ = (((KI) * 3) * 64 + lane) * 8; \
    short8 b0_ = *(const short8*)(s_whi + fo_); \
    short8 b1_ = *(const short8*)(s_whi + fo_ + 512); \
    short8 b2_ = *(const short8*)(s_whi + fo_ + 1024); \
    aR  = MFMA(ah_, b0_, aR); \
    aZ  = MFMA(ah_, b1_, aZ); \
    aNh = MFMA(ah_, b2_, aNh); \
} while (0)

#define CH_ISSUE(LDFN, B, KC) do { \
    const short* hp_ = hrd + (size_t)(KC) * 16384; \
    hb[(B) + 0] = LDFN(hp_); \
    hb[(B) + 1] = LDFN(hp_ + 4096); \
    hb[(B) + 2] = LDFN(hp_ + 8192); \
    hb[(B) + 3] = LDFN(hp_ + 12288); \
} while (0)

#define CH_CONS(B, KC) do { \
    const int kb_ = 4 + 4 * (KC); \
    HCONS((B) + 0, kb_ + 0); \
    HCONS((B) + 1, kb_ + 1); \
    HCONS((B) + 2, kb_ + 2); \
    HCONS((B) + 3, kb_ + 3); \
} while (0)

#define SPIN_CH(KC) do { \
    while (ld_ws(&s_sub2[CHN][(KC) >> 1]) < (unsigned)step) __builtin_amdgcn_s_sleep(2); \
} while (0)

#define REGION2(LDFN) do { \
    i32x4 hb[16]; \
    const int k0_ = r0;            const int k1_ = (r0 + 1) & 7; \
    const int k2_ = (r0 + 2) & 7;  const int k3_ = (r0 + 3) & 7; \
    const int k4_ = (r0 + 4) & 7;  const int k5_ = (r0 + 5) & 7; \
    const int k6_ = (r0 + 6) & 7;  const int k7_ = (r0 + 7) & 7; \
    SPIN_CH(k0_); CH_ISSUE(LDFN, 0,  k0_); \
    SPIN_CH(k1_); CH_ISSUE(LDFN, 4,  k1_); \
    SPIN_CH(k2_); CH_ISSUE(LDFN, 8,  k2_); \
    SPIN_CH(k3_); CH_ISSUE(LDFN, 12, k3_); \
    WAITVM(12); CH_CONS(0,  k0_); SPIN_CH(k4_); CH_ISSUE(LDFN, 0,  k4_); \
    WAITVM(12); CH_CONS(4,  k1_); SPIN_CH(k5_); CH_ISSUE(LDFN, 4,  k5_); \
    WAITVM(12); CH_CONS(8,  k2_); SPIN_CH(k6_); CH_ISSUE(LDFN, 8,  k6_); \
    WAITVM(12); CH_CONS(12, k3_); SPIN_CH(k7_); CH_ISSUE(LDFN, 12, k7_); \
    WAITVM(12); CH_CONS(0,  k4_); \
    WAITVM(8);  CH_CONS(4,  k5_); \
    WAITVM(4);  CH_CONS(8,  k6_); \
    WAITVM(0);  CH_CONS(12, k7_); \
} while (0)

// ---------- region-1 helpers (x part, 3-term hi/lo) ----------
#define R1TRIPLE(KI) do { \
    short8 ah_, al_; \
    _Pragma("unroll") \
    for (int j = 0; j < 8; ++j) { short h2_, l2_; f2pair(f[j], h2_, l2_); ah_[j] = h2_; al_[j] = l2_; } \
    const int fo_ = (((KI) * 3) * 64 + lane) * 8; \
    short8 b0_ = *(const short8*)(s_whi + fo_); \
    short8 b1_ = *(const short8*)(s_whi + fo_ + 512); \
    short8 b2_ = *(const short8*)(s_whi + fo_ + 1024); \
    aR  = MFMA(ah_, b0_, aR);  aR  = MFMA(ah_, L0r[KI], aR);  aR  = MFMA(al_, b0_, aR); \
    aZ  = MFMA(ah_, b1_, aZ);  aZ  = MFMA(ah_, L1r[KI], aZ);  aZ  = MFMA(al_, b1_, aZ); \
    aNi = MFMA(ah_, b2_, aNi); aNi = MFMA(ah_, L2r[KI], aNi); aNi = MFMA(al_, b2_, aNi); \
} while (0)

#define LOADF(KI) do { \
    const float* s_ = feats + ((size_t)brow * 159 + step) * 64 + (KI) * 32 + q * 8; \
    f32x4 a_ = ((const f32x4*)s_)[0], b_ = ((const f32x4*)s_)[1]; \
    _Pragma("unroll") for (int j = 0; j < 4; ++j) { f[j] = a_[j]; f[4 + j] = b_[j]; } \
} while (0)

#define LOADL(KI) do { \
    const float* s_ = labels + ((size_t)brow * 128 + step) * 64 + ((KI) - 2) * 32 + q * 8; \
    f32x4 a_ = ((const f32x4*)s_)[0], b_ = ((const f32x4*)s_)[1]; \
    _Pragma("unroll") for (int j = 0; j < 4; ++j) { f[j] = a_[j]; f[4 + j] = b_[j]; } \
} while (0)

#define LOADP(KI) do { \
    const u64* pp_ = (const u64*)(ps_f32 + (size_t)brow * 64 + ((KI) - 2) * 32 + q * 8); \
    _Pragma("unroll") for (int j = 0; j < 4; ++j) { \
        u64 v_ = ldq_dev(pp_ + j); \
        f[2 * j]     = __uint_as_float((unsigned)v_); \
        f[2 * j + 1] = __uint_as_float((unsigned)(v_ >> 32)); } \
} while (0)

// chain-local sync: 4 waves arrive (lane0 adds), all spin on LDS counter.
// DS ops are in-order per wave, so writes before the add are visible after
// the observing load.
#define CHAIN_SYNC() do { \
    cs_tgt += 4u; \
    if (lane == 0) add_ws(&s_cs[CHN], 1u); \
    while (ld_ws(&s_cs[CHN]) < cs_tgt) __builtin_amdgcn_s_sleep(1); \
} while (0)

// ---------- main persistent kernel ----------
// TWO-CHAIN design: rows 0-63 (waves 0-3, chain 0) and rows 64-127 (waves
// 4-7, chain 1) are fully independent recurrences. Each chain has its own
// flags/counters/gating; NO block barriers anywhere in the step loop. Chain 1
// is staggered ~4us at start; since each chain's cadence depends only on
// same-chain producers, the anti-phase offset is self-consistent -> one
// chain's compute fills the other chain's dependency waits on the CU.
//  - h(t) fresh 1 MB slot; far-atomic swap publish, drain deferred (R5).
//  - hflag[(r*64+c)*2+CH]; wave wv4 polls same-chain producers [16wv4,+16).
//  - ps phase: owned by chain (c>>5); chain-local LDS sync, 256 threads.
//  - Per-chain same-XCD rhythm preserved (FETCH guard; R8 lesson).
__global__ __launch_bounds__(512, 2) void gru_main(
    const float* __restrict__ feats, const float* __restrict__ labels,
    const float* __restrict__ bi,    const float* __restrict__ bh,
    const float* __restrict__ Wd,    const float* __restrict__ bd,
    const short* __restrict__ whi_sw, const short* __restrict__ wlo_x,
    short* __restrict__ h16,         float* __restrict__ ps_f32,
    float* __restrict__ out,
    unsigned* __restrict__ hflag,    // [4r][64c][2ch] @64B
    unsigned* __restrict__ pflag,    // [4r][64c] @64B
    int nslots)                      // 160 = fresh-per-step (cached), 2 = ring (nc)
{
    __shared__ short s_whi[SLAB_ELEMS];   // 108 KB resident W_hi slab (fragment order)
    __shared__ float s_ps[2048];          // ps-phase h staging (2 rows x 1024)
    __shared__ short s_tr[8][16][18];     // epilogue transpose tiles (padded: bank-safe)
    __shared__ unsigned s_sub2[2][4];     // per-chain chunk-ready words
    __shared__ unsigned s_arrD2[2];       // deferred publish arrivals per chain
    __shared__ unsigned s_arrI2[2];       // immediate publish arrivals per chain
    __shared__ unsigned s_cs[2];          // chain-sync counters

    const int tid  = threadIdx.x;
    const int lane = tid & 63;
    const int wv   = tid >> 6;            // wave 0..7 (global)
    const int CHN  = wv >> 2;             // chain 0 (rows 0-63) / 1 (rows 64-127)
    const int wv4  = wv & 3;              // wave index within chain
    const int q    = lane >> 4;
    const int n16  = lane & 15;
    const int c    = blockIdx.x & 63;     // out-group: h-cols [16c, 16c+16)
    const int r    = blockIdx.x >> 6;     // batch-group: rows [128r, 128r+128)
    const int r0   = c & 7;               // XCD id: rotation start chunk
    const bool cached = (nslots > 2);
    unsigned cs_tgt = 0;                  // chain-sync target (per thread)

    // init sync state + stage W_hi slab
    if (tid < 8)   s_sub2[tid >> 2][tid & 3] = 0;
    if (tid == 8)  s_arrD2[0] = 0;
    if (tid == 9)  s_arrD2[1] = 0;
    if (tid == 10) s_arrI2[0] = 0;
    if (tid == 11) s_arrI2[1] = 0;
    if (tid == 12) s_cs[0] = 0;
    if (tid == 13) s_cs[1] = 0;
    {
        const f32x4* src = (const f32x4*)(whi_sw + (size_t)c * SLAB_ELEMS);
        f32x4* dst = (f32x4*)s_whi;
        for (int i = tid; i < SLAB_ELEMS / 8; i += 512) dst[i] = src[i];
    }
    __syncthreads();

    // anti-phase stagger: chain 1 starts ~4.2us late; offset is stable since
    // each chain depends only on same-chain (equally staggered) producers.
    if (CHN == 1) { __builtin_amdgcn_s_sleep(127); __builtin_amdgcn_s_sleep(32); }

    const int mbase = r * 128 + wv * 16;  // this wave's 16 batch rows (global)
    const int brow  = mbase + n16;        // A-fragment row for this lane
    const int row_r = c * 16 + n16;       // gate row == D col
    const float bias_r  = bi[row_r] + bh[row_r];
    const float bias_z  = bi[1024 + row_r] + bh[1024 + row_r];
    const float bias_ni = bi[2048 + row_r];
    const float bias_nh = bh[2048 + row_r];

    unsigned* my_hflag = hflag + (((r * 64 + c) * 2) + CHN) * FS;
    unsigned* my_pflag = pflag + (r * 64 + c) * FS;
    // wave's 16 same-chain h-producers [16wv4, 16wv4+16)
    const unsigned* hfp16 = hflag + (((r * 64 + 16 * wv4 + (lane & 15)) * 2) + CHN) * FS;
    // wave's 8 ps-producers (global wv encodes chain: c' in [8wv, 8wv+8))
    const unsigned* pfp   = pflag + (r * 64 + 8 * wv + (lane & 7)) * FS;

    // hoist region-1 W_lo fragments (step-invariant): 12 x short8 = 48 VGPRs
    short8 L0r[4], L1r[4], L2r[4];
#pragma unroll
    for (int ki = 0; ki < 4; ++ki) {
        const short* base = wlo_x + (size_t)(((c * 4 + ki) * 3) * 64 + lane) * 8;
        L0r[ki] = *(const short8*)(base);
        L1r[ki] = *(const short8*)(base + 512);
        L2r[ki] = *(const short8*)(base + 1024);
    }

    float hold[4] = {0.f, 0.f, 0.f, 0.f};  // h carried fp32 in-register

    for (int step = 0; step < NSTEPS; ++step) {
        const bool dec = (step >= SENC);
        const unsigned tgt = (unsigned)(step + 1);
        const int rslot = cached ? step       : (step & 1);
        const int wslot = cached ? (step + 1) : ((step + 1) & 1);
        const short* hrd = h16 + (size_t)rslot * HB16 + (size_t)r * XSLICE
                         + (size_t)(wv * 16 + n16) * 16 + (q & 1) * 8 + (q >> 1) * 2048;
        short* hwr = h16 + (size_t)wslot * HB16 + (size_t)r * XSLICE;

        // decoder: pflag prefetch seed (RT hides under region1's F-triples)
        unsigned pf_pre = 0xFFFFFFFFu;
        if (dec) pf_pre = ldu_dev(pfp);

        floatx4 aR  = (floatx4){bias_r,  bias_r,  bias_r,  bias_r};
        floatx4 aZ  = (floatx4){bias_z,  bias_z,  bias_z,  bias_z};
        floatx4 aNi = (floatx4){bias_ni, bias_ni, bias_ni, bias_ni};
        floatx4 aNh = (floatx4){bias_nh, bias_nh, bias_nh, bias_nh};

        // ---- region 1 (x part), deferred publish-finalize in the middle ----
        {
            float f[8];
            LOADF(0); R1TRIPLE(0);
            LOADF(1); R1TRIPLE(1);

            // finalize h(step) publish (swaps issued at epilogue of step-1):
            // drain hides under region1 compute; 4th chain wave sets flag.
            if (step > 0 && step <= SENC - 1) {
                WAITVM(0);
                if (lane == 0) {
                    unsigned old = add_ws(&s_arrD2[CHN], 1u);
                    if (old == 4u * (unsigned)step - 1u)
                        stu_dev(my_hflag, (unsigned)step);
                }
            }

            if (!dec) {
                LOADL(2); R1TRIPLE(2);
                LOADL(3); R1TRIPLE(3);
            } else {
                // ps(step) ready: per-wave seeded poll, NO barrier
                if (!__all(pf_pre >= (unsigned)step)) {
                    while (!__all(ldu_dev(pfp) >= (unsigned)step))
                        __builtin_amdgcn_s_sleep(2);
                }
                LOADP(2); R1TRIPLE(2);
                LOADP(3); R1TRIPLE(3);
            }
        }

        // ---- per-chain h-ready poll + chunk-gated, XCD-rotated region 2 ----
        if (step > 0) {
            while (!__all(ldu_dev(hfp16) >= (unsigned)step))
                __builtin_amdgcn_s_sleep(2);
            if (lane == 0) st_ws(&s_sub2[CHN][wv4], (unsigned)step);
            if (cached) { REGION2(ld_sc0_16); }   // L2-cached; XCD multicast
            else        { REGION2(ld_nc16); }     // ring-2 fallback: coherence-point direct
        }

        // ---- epilogue: GRU update; far-atomic publish of own tile ----
        {
#pragma unroll
            for (int i = 0; i < 4; ++i) {
                float rr = sigm(aR[i]);
                float zz = sigm(aZ[i]);
                float nn = tanh_fast(aNi[i] + rr * aNh[i]);
                float hv = (1.0f - zz) * nn + zz * hold[i];
                hold[i] = hv;
                s_tr[wv][q * 4 + i][n16] = f2bf(hv);   // D row = q*4+i, col = n16
            }
            WAITLGKM;
            const int rr2 = lane >> 2, seg = lane & 3;
            u64 v = *(const u64*)&s_tr[wv][rr2][seg * 4];
            st_swap8(hwr + (size_t)c * 2048 + (size_t)(wv * 16 + rr2) * 16 + seg * 4, v);
            if (step >= SENC - 1) {                    // immediate publish (ps needs it)
                WAITVM(0);
                if (lane == 0) {
                    unsigned old = add_ws(&s_arrI2[CHN], 1u);
                    if (old == 4u * (unsigned)(step - (SENC - 1) + 1) - 1u)
                        stu_dev(my_hflag, tgt);
                }
            }
        }

        // ---- ps phase: owning chain only (rows 2c,2c+1 in chain c>>5) ----
        if (step >= SENC - 1 && CHN == (c >> 5)) {
            const int ot = step - (SENC - 1);          // output time 0..31
            const int prow0 = r * 128 + 2 * c;         // this block's 2 ps rows (global)
            // verify all 64 same-chain producers published h(step+1)
            while (!__all(ldu_dev(hfp16) >= tgt))
                __builtin_amdgcn_s_sleep(2);
            CHAIN_SYNC();
            {                                           // gather: 256 chain threads
                const int ctid = wv4 * 64 + lane;
                const int rl = ctid >> 7, rest = ctid & 127;
                const int ct = rest >> 1, half = rest & 1;
                const short* src = hwr + (size_t)ct * 2048
                                 + (size_t)(2 * c + rl) * 16 + half * 8;
                i32x4 v = ld_nc16(src);
                WAITVM(0);
                short8 s = *(short8*)&v;
#pragma unroll
                for (int j = 0; j < 8; ++j)
                    s_ps[rl * 1024 + ct * 16 + half * 8 + j] = bf2f(s[j]);
            }
            CHAIN_SYNC();
            // dedup'd dot: 256 threads, each does BOTH rows for (o, K-quarter e)
            const int ctid = wv4 * 64 + lane;
            const int o = ctid >> 2, e = ctid & 3;
            const float* wrow = Wd + (size_t)o * 1024;
            float acc0 = 0.0f, acc1 = 0.0f;
#pragma unroll 8
            for (int j = 0; j < 64; ++j) {
                const int k = j * 16 + e * 4;
                f32x4 w  = *(const f32x4*)(wrow + k);
                f32x4 a4 = *(const f32x4*)(s_ps + k);
                f32x4 b4 = *(const f32x4*)(s_ps + 1024 + k);
                acc0 += a4[0] * w[0] + a4[1] * w[1] + a4[2] * w[2] + a4[3] * w[3];
                acc1 += b4[0] * w[0] + b4[1] * w[1] + b4[2] * w[2] + b4[3] * w[3];
            }
            acc0 += __shfl_xor(acc0, 1); acc0 += __shfl_xor(acc0, 2);
            acc1 += __shfl_xor(acc1, 1); acc1 += __shfl_xor(acc1, 2);
            if (e == 0) {
                float v0 = acc0 + bd[o];
                float v1 = acc1 + bd[o];
                out[((size_t)ot * 512 + prow0)     * 64 + o] = v0;
                out[((size_t)ot * 512 + prow0 + 1) * 64 + o] = v1;
                st_swap4(ps_f32 + (size_t)prow0       * 64 + o, __float_as_uint(v0));
                st_swap4(ps_f32 + (size_t)(prow0 + 1) * 64 + o, __float_as_uint(v1));
            }
            WAITVM(0);
            CHAIN_SYNC();
            if (wv4 == 0 && lane == 0) stu_dev(my_pflag, tgt);  // ps(step+1) published
        }
    }
}

extern "C" void kernel_launch(void* const* d_in, const int* in_sizes, int n_in,
                              void* d_out, int out_size, void* d_ws, size_t ws_size,
                              hipStream_t stream) {
    const float* feats  = (const float*)d_in[0];
    const float* labels = (const float*)d_in[1];
    const float* Wi     = (const float*)d_in[2];
    const float* Wh     = (const float*)d_in[3];
    const float* bi     = (const float*)d_in[4];
    const float* bh     = (const float*)d_in[5];
    const float* Wd     = (const float*)d_in[6];
    const float* bd     = (const float*)d_in[7];
    float* out = (float*)d_out;

    char* ws = (char*)d_ws;
    short*    whi_sw = (short*)(ws);                   //  7,077,888 B
    short*    wlo_x  = (short*)(ws + 7077888);         //    786,432 B
    float*    ps_f32 = (float*)(ws + 7864320);         //    131,072 B
    unsigned* pflag  = (unsigned*)(ws + 7995392);      //     16,384 B (4r x 64c x 64B)
    unsigned* hflag  = (unsigned*)(ws + 8011776);      //     32,768 B (4r x 64c x 2ch x 64B)
    short*    h16    = (short*)(ws + 8388608);         //  nslots x 1 MB h slots

    // cached mode needs slots 0..159 (slot t = h(t)); fallback = 2-slot ring + nc reads
    const size_t need = 8388608ull + 160ull * 1048576ull;  // 176,160,768 B
    int nslots = (ws_size >= need) ? 160 : 2;

    // zero flag state (pflag + hflag)
    hipMemsetAsync(ws + 7995392, 0, 49152, stream);

    setup_swizzle<<<FRAG_TOTAL / 256, 256, 0, stream>>>(Wi, Wh, whi_sw, wlo_x);

    void* args[] = {(void*)&feats, (void*)&labels, (void*)&bi, (void*)&bh,
                    (void*)&Wd, (void*)&bd, (void*)&whi_sw, (void*)&wlo_x,
                    (void*)&h16, (void*)&ps_f32, (void*)&out,
                    (void*)&hflag, (void*)&pflag, (void*)&nslots};
    hipLaunchCooperativeKernel(reinterpret_cast<void*>(gru_main),
                               dim3(256), dim3(512), args, 0, stream);
}